// Round 5
// baseline (357.718 us; speedup 1.0000x reference)
//
#include <hip/hip_runtime.h>
#include <hip/hip_bf16.h>

#define NN 50000
#define NPAD 50048   // h rows incl. zero rows 50000..50047 (gemm grid coverage)
#define EE 1600000
#define NB 391       // buckets of 128 rows (391*128 = 50048 >= NN)
#define CAPB 4608    // per-bucket global capacity; mean 4092, sd ~64 -> +8 sigma
#define CPAD 16      // one counter per 64B line
#define EPB 4096     // edges per k_bucket block -> 391 blocks
#define BCAP 28      // per-(block,bucket) LDS cap; mean 10.5 (+5.5 sigma, spill-safe)

typedef __attribute__((ext_vector_type(8))) short short8;
typedef __attribute__((ext_vector_type(4))) float floatx4;

// ---- dual-dtype load: external float tensors are either f32 or bf16 (flag).
__device__ __forceinline__ float ldext(const void* p, long i, int f32) {
    return f32 ? ((const float*)p)[i]
               : __bfloat162float(((const __hip_bfloat16*)p)[i]);
}

__device__ __forceinline__ float b2f(unsigned short u) {
    unsigned int x = ((unsigned int)u) << 16;
    float f; __builtin_memcpy(&f, &x, 4); return f;
}
__device__ __forceinline__ unsigned short f2b(float f) {
    __hip_bfloat16 h = __float2bfloat16(f);   // round-to-nearest-even
    unsigned short u; __builtin_memcpy(&u, &h, 2); return u;
}
__device__ __forceinline__ float asf(unsigned int x) {
    float f; __builtin_memcpy(&f, &x, 4); return f;
}

// ---------------- pass A: LDS binning + lane-parallel flush (+flag in blk 0) --
__global__ void k_bucket(const int* __restrict__ row, const int* __restrict__ col,
                         int* __restrict__ bcur, unsigned int* __restrict__ bdata,
                         const unsigned short* __restrict__ xu, int* __restrict__ flag) {
    __shared__ int lcnt[NB];
    __shared__ unsigned binned[NB * BCAP];   // ~43.8 KB
    __shared__ int dcnt;
    int tid = threadIdx.x;
    if (blockIdx.x == 0) {                   // input-dtype detection (once)
        if (tid == 0) dcnt = 0;
        __syncthreads();
        int local = 0;
        for (int j = 0; j < 16; ++j) {
            unsigned short u = xu[2 * (tid + 256 * j)];
            int ex = (u >> 7) & 0xFF;
            if (ex == 0xFF || ex < 0x60) local++;
        }
        atomicAdd(&dcnt, local);
        __syncthreads();
        if (tid == 0) flag[0] = (dcnt > 256) ? 1 : 0;
    }
    long base = (long)blockIdx.x * EPB;
    int nedge = (int)min((long)EPB, (long)EE - base);   // always multiple of 4
    for (int k = tid; k < NB; k += 256) lcnt[k] = 0;
    __syncthreads();
    const int4* r4 = (const int4*)(row + base);
    const int4* c4 = (const int4*)(col + base);
    for (int j = tid; j < (nedge >> 2); j += 256) {
        int4 rr = r4[j], cc = c4[j];
        #pragma unroll
        for (int t = 0; t < 4; ++t) {
            int r = (&rr.x)[t], c = (&cc.x)[t];
            int b = r >> 7;
            unsigned rec = ((unsigned)(r & 127) << 16) | (unsigned)c;
            int p = atomicAdd(&lcnt[b], 1);
            if (p < BCAP) binned[b * BCAP + p] = rec;
            else {                               // rare spill: direct global append
                int gp = atomicAdd(&bcur[b * CPAD], 1);
                if (gp < CAPB) bdata[(long)b * CAPB + gp] = rec;
            }
        }
    }
    __syncthreads();
    for (int b = tid; b < NB; b += 256) {
        int n = min(lcnt[b], BCAP);
        if (!n) continue;
        int gb = atomicAdd(&bcur[b * CPAD], n);
        long dst = (long)b * CAPB;
        for (int j = 0; j < n; ++j)
            if (gb + j < CAPB) bdata[dst + gb + j] = binned[b * BCAP + j];
    }
}

// ---------------- fused: degree count + prefix + row_ptr/dis + scatter -------
__global__ void k_csr(const int* __restrict__ bcur, const unsigned* __restrict__ bdata,
                      int* __restrict__ row_ptr, float* __restrict__ dis,
                      unsigned short* __restrict__ csr_col) {
    __shared__ unsigned recs[CAPB];          // 18.4 KB
    __shared__ int cnt[128];
    __shared__ int incl[128];
    __shared__ int curs[128];
    __shared__ int redu[4];
    int b = blockIdx.x, tid = threadIdx.x;
    int lane = tid & 63, wid = tid >> 6;
    int part = 0;
    for (int j = tid; j < b; j += 256) part += min(bcur[j * CPAD], CAPB);
    #pragma unroll
    for (int off = 32; off; off >>= 1) part += __shfl_xor(part, off);
    if (lane == 0) redu[wid] = part;
    if (tid < 128) cnt[tid] = 0;
    __syncthreads();
    int base = redu[0] + redu[1] + redu[2] + redu[3];
    int n = min(bcur[b * CPAD], CAPB);
    const unsigned* dp = bdata + (long)b * CAPB;
    for (int i = tid; i < n; i += 256) {
        unsigned rec = dp[i];
        recs[i] = rec;
        atomicAdd(&cnt[(rec >> 16) & 127], 1);
    }
    __syncthreads();
    if (tid < 128) {
        int x = cnt[tid];
        #pragma unroll
        for (int off = 1; off < 64; off <<= 1) {
            int y = __shfl_up(x, off);
            if (lane >= off) x += y;
        }
        incl[tid] = x;
    }
    __syncthreads();
    int r0 = b << 7;
    if (tid < 128) {
        int ic = incl[tid] + (wid == 1 ? incl[63] : 0);
        int excl = base + ic - cnt[tid];
        curs[tid] = excl;
        int r = r0 + tid;
        if (r <= NN) row_ptr[r] = excl;
        if (r < NN) dis[r] = rsqrtf((float)(cnt[tid] + 1));
    }
    __syncthreads();
    for (int i = tid; i < n; i += 256) {
        unsigned rec = recs[i];
        int p = atomicAdd(&curs[(rec >> 16) & 127], 1);
        csr_col[p] = (unsigned short)(rec & 0xFFFF);
    }
}

// ---------------- dense h' = dis_n * inv_prev * (X @ W), MFMA bf16 ----------
// For EXT=false, X holds UN-normalized relu'd prev-layer values; the deferred
// l2norm row scale inv = 1/max(sqrt(sumsq),1e-12) commutes with @W and is
// applied post-MFMA. Rows NN..NPAD-1 are zero pad for k_agg's uniform loop.
template <bool EXT>
__global__ void k_gemm(const void* __restrict__ X, const void* __restrict__ W,
                       const int* __restrict__ flag, const float* __restrict__ dis,
                       const float* __restrict__ sq,   // prev-layer sumsq (null if EXT)
                       unsigned short* __restrict__ Hout) {
    __shared__ __align__(16) unsigned short xs[64 * 72];
    int tid = threadIdx.x;
    int n0 = blockIdx.x * 64;
    const int f32 = flag[0];
    for (int idx = tid; idx < 4096; idx += 256) {
        int nn = idx >> 6, k = idx & 63;
        int n = n0 + nn;
        unsigned short v = 0;
        if (n < NN) {
            long ofs = (long)n * 64 + k;
            if (EXT) v = f32 ? f2b(((const float*)X)[ofs]) : ((const unsigned short*)X)[ofs];
            else     v = ((const unsigned short*)X)[ofs];
        }
        xs[nn * 72 + k] = v;
    }
    __syncthreads();
    int lane = tid & 63, wid = tid >> 6;
    int m0 = wid * 16;
    int quad = lane >> 4, nl = lane & 15;
    short8 a0 = *(const short8*)(xs + (m0 + nl) * 72 + quad * 8);
    short8 a1 = *(const short8*)(xs + (m0 + nl) * 72 + quad * 8 + 32);
    floatx4 acc[4];
    const unsigned short* Wb = (const unsigned short*)W;
    const float* Wf = (const float*)W;
    #pragma unroll
    for (int ct = 0; ct < 4; ++ct) {
        short8 b0, b1;
        int n = ct * 16 + nl;
        #pragma unroll
        for (int j = 0; j < 8; ++j) {
            int k0 = quad * 8 + j;
            b0[j] = (short)(f32 ? f2b(Wf[k0 * 64 + n]) : Wb[k0 * 64 + n]);
            b1[j] = (short)(f32 ? f2b(Wf[(k0 + 32) * 64 + n]) : Wb[(k0 + 32) * 64 + n]);
        }
        floatx4 c = {0.f, 0.f, 0.f, 0.f};
        c = __builtin_amdgcn_mfma_f32_16x16x32_bf16(a0, b0, c, 0, 0, 0);
        c = __builtin_amdgcn_mfma_f32_16x16x32_bf16(a1, b1, c, 0, 0, 0);
        acc[ct] = c;
    }
    #pragma unroll
    for (int r = 0; r < 4; ++r) {
        int node = n0 + m0 + quad * 4 + r;   // always < NPAD
        if (node < NN) {
            float dn = dis[node];
            if (!EXT) dn *= 1.f / fmaxf(sqrtf(sq[node]), 1e-12f);  // deferred l2norm
            #pragma unroll
            for (int ct = 0; ct < 4; ++ct)
                Hout[(long)node * 64 + ct * 16 + nl] = f2b(dn * acc[ct][r]);
        } else {                              // zero pad rows NN..NPAD-1
            #pragma unroll
            for (int ct = 0; ct < 4; ++ct)
                Hout[(long)node * 64 + ct * 16 + nl] = 0;
        }
    }
}

// ---------------- per-node aggregation + bias + relu (norm deferred) ---------
// XCD-partitioned feature planes: blocks dispatch round-robin to XCDs
// (xcd = bid & 7). XCDs 0-3 gather only bytes [0,64) of each h row (features
// 0-31), XCDs 4-7 bytes [64,128): per-XCD L2 hot set = 3.2 MB < 4 MB -> L2
// resident. Writes UN-normalized relu'd bf16 + atomic per-node sumsq; the
// consumer applies the row scale (commutes with @W). Uniform 64-edge loop,
// 8 gathers of 64B in flight per lane; pad slots clamp to zero row NN.
__global__ void k_agg(const uint4* __restrict__ hp128, const int* __restrict__ row_ptr,
                      const unsigned short* __restrict__ csr_col,
                      const float* __restrict__ dis, const void* __restrict__ bias,
                      const int* __restrict__ flag,
                      unsigned short* __restrict__ eo /* [N,64] bf16 raw */,
                      float* __restrict__ sq /* [N] sumsq */) {
    int lane = threadIdx.x & 63, wid = threadIdx.x >> 6;
    int bid = blockIdx.x;
    int plane = (bid >> 2) & 1;              // xcd = bid&7; plane = xcd>>2
    int grp = (bid >> 3) * 4 + (bid & 3);    // node group of 8
    int half = lane >> 5;
    int i = grp * 8 + wid * 2 + half;
    bool valid = (i < NN);
    int iv = valid ? i : 0;
    int q  = (lane >> 2) & 7;   // edge slot (8 per node)
    int fl = lane & 3;          // 16B chunk within the 64B plane row
    const int fo = plane * 4 + fl;           // uint4 offset within 128B row
    float2 A0 = {0,0}, A1 = {0,0}, A2 = {0,0}, A3 = {0,0};
    #define ADDU(u) do { \
        A0.x += asf((u).x << 16); A0.y += asf((u).x & 0xFFFF0000u); \
        A1.x += asf((u).y << 16); A1.y += asf((u).y & 0xFFFF0000u); \
        A2.x += asf((u).z << 16); A2.y += asf((u).z & 0xFFFF0000u); \
        A3.x += asf((u).w << 16); A3.y += asf((u).w & 0xFFFF0000u); } while (0)
    if (valid && q == 0) {      // self-loop term
        uint4 u = hp128[(long)iv * 8 + fo];
        ADDU(u);
    }
    int e  = valid ? row_ptr[iv] : 0;
    int e1 = valid ? row_ptr[iv + 1] : 0;
    while (e < e1) {
        int i0 = e + q,      i1 = e + 8 + q,  i2 = e + 16 + q, i3 = e + 24 + q;
        int i4 = e + 32 + q, i5 = e + 40 + q, i6 = e + 48 + q, i7 = e + 56 + q;
        int c0 = (i0 < e1) ? (int)__builtin_nontemporal_load(csr_col + i0) : NN;
        int c1 = (i1 < e1) ? (int)__builtin_nontemporal_load(csr_col + i1) : NN;
        int c2 = (i2 < e1) ? (int)__builtin_nontemporal_load(csr_col + i2) : NN;
        int c3 = (i3 < e1) ? (int)__builtin_nontemporal_load(csr_col + i3) : NN;
        int c4 = (i4 < e1) ? (int)__builtin_nontemporal_load(csr_col + i4) : NN;
        int c5 = (i5 < e1) ? (int)__builtin_nontemporal_load(csr_col + i5) : NN;
        int c6 = (i6 < e1) ? (int)__builtin_nontemporal_load(csr_col + i6) : NN;
        int c7 = (i7 < e1) ? (int)__builtin_nontemporal_load(csr_col + i7) : NN;
        uint4 u0 = hp128[(long)c0 * 8 + fo];
        uint4 u1 = hp128[(long)c1 * 8 + fo];
        uint4 u2 = hp128[(long)c2 * 8 + fo];
        uint4 u3 = hp128[(long)c3 * 8 + fo];
        uint4 u4 = hp128[(long)c4 * 8 + fo];
        uint4 u5 = hp128[(long)c5 * 8 + fo];
        uint4 u6 = hp128[(long)c6 * 8 + fo];
        uint4 u7 = hp128[(long)c7 * 8 + fo];
        ADDU(u0); ADDU(u1); ADDU(u2); ADDU(u3);
        ADDU(u4); ADDU(u5); ADDU(u6); ADDU(u7);
        e += 64;
    }
    #undef ADDU
    // butterfly over the 8 edge slots (lane bits 2..4)
    #pragma unroll
    for (int off = 4; off < 32; off <<= 1) {
        A0.x += __shfl_xor(A0.x, off); A0.y += __shfl_xor(A0.y, off);
        A1.x += __shfl_xor(A1.x, off); A1.y += __shfl_xor(A1.y, off);
        A2.x += __shfl_xor(A2.x, off); A2.y += __shfl_xor(A2.y, off);
        A3.x += __shfl_xor(A3.x, off); A3.y += __shfl_xor(A3.y, off);
    }
    const int f32 = flag[0];
    float di = dis[iv];
    int fb = plane * 32 + fl * 8;            // feature base for this lane
    float v0 = fmaf(di, A0.x, ldext(bias, fb + 0, f32));
    float v1 = fmaf(di, A0.y, ldext(bias, fb + 1, f32));
    float v2 = fmaf(di, A1.x, ldext(bias, fb + 2, f32));
    float v3 = fmaf(di, A1.y, ldext(bias, fb + 3, f32));
    float v4 = fmaf(di, A2.x, ldext(bias, fb + 4, f32));
    float v5 = fmaf(di, A2.y, ldext(bias, fb + 5, f32));
    float v6 = fmaf(di, A3.x, ldext(bias, fb + 6, f32));
    float v7 = fmaf(di, A3.y, ldext(bias, fb + 7, f32));
    v0 = fmaxf(v0, 0.f); v1 = fmaxf(v1, 0.f); v2 = fmaxf(v2, 0.f); v3 = fmaxf(v3, 0.f);
    v4 = fmaxf(v4, 0.f); v5 = fmaxf(v5, 0.f); v6 = fmaxf(v6, 0.f); v7 = fmaxf(v7, 0.f);
    float s = fmaf(v0, v0, fmaf(v1, v1, fmaf(v2, v2, v3 * v3)))
            + fmaf(v4, v4, fmaf(v5, v5, fmaf(v6, v6, v7 * v7)));
    // reduce partial sumsq across the 4 fl lanes (within the q==0 group)
    s += __shfl_xor(s, 1);
    s += __shfl_xor(s, 2);
    if (valid && q == 0) {
        union { unsigned short us[8]; uint4 v; } pk;
        pk.us[0] = f2b(v0); pk.us[1] = f2b(v1);
        pk.us[2] = f2b(v2); pk.us[3] = f2b(v3);
        pk.us[4] = f2b(v4); pk.us[5] = f2b(v5);
        pk.us[6] = f2b(v6); pk.us[7] = f2b(v7);
        *(uint4*)(eo + (long)i * 64 + fb) = pk.v;
        if (fl == 0) atomicAdd(&sq[i], s);
    }
}

// ---------------- head: emb @ Wlin + blin + log_softmax, MFMA ----------------
// emb holds UN-normalized layer outputs; per-layer row scale invL applied to
// each layer's partial MFMA accumulator (scale commutes with @Wlin segment).
__global__ void k_out(const unsigned short* __restrict__ emb, const void* __restrict__ Wlin,
                      const void* __restrict__ blin, const int* __restrict__ flag,
                      const float* __restrict__ sumsq /* [3][N] */,
                      void* __restrict__ out) {
    int tid = threadIdx.x, lane = tid & 63, wid = tid >> 6;
    int quad = lane >> 4, nl = lane & 15;
    int base = blockIdx.x * 64 + wid * 16;
    const int f32 = flag[0];
    const unsigned short* Wb = (const unsigned short*)Wlin;
    const float* Wf = (const float*)Wlin;
    int ia = min(base + nl, NN - 1);     // A-row node (guarded store later)
    floatx4 cL[3];
    #pragma unroll
    for (int L = 0; L < 3; ++L) cL[L] = floatx4{0.f, 0.f, 0.f, 0.f};
    #pragma unroll
    for (int L = 0; L < 3; ++L) {
        #pragma unroll
        for (int kh = 0; kh < 2; ++kh) {
            short8 b;
            #pragma unroll
            for (int j = 0; j < 8; ++j) {
                int k = L * 64 + kh * 32 + quad * 8 + j;
                b[j] = (short)(f32 ? f2b(Wf[k * 16 + nl]) : Wb[k * 16 + nl]);
            }
            int ko = kh * 32 + quad * 8;
            short8 a = *(const short8*)(emb + (long)L * NN * 64 + (long)ia * 64 + ko);
            cL[L] = __builtin_amdgcn_mfma_f32_16x16x32_bf16(a, b, cL[L], 0, 0, 0);
        }
    }
    float bl = ldext(blin, nl, f32);
    #pragma unroll
    for (int r = 0; r < 4; ++r) {
        int node = base + quad * 4 + r;    // uniform across the 16 nl lanes
        if (node < NN) {
            float i0 = 1.f / fmaxf(sqrtf(sumsq[node]), 1e-12f);
            float i1 = 1.f / fmaxf(sqrtf(sumsq[NN + node]), 1e-12f);
            float i2 = 1.f / fmaxf(sqrtf(sumsq[2 * NN + node]), 1e-12f);
            float v = fmaf(i0, cL[0][r], fmaf(i1, cL[1][r], fmaf(i2, cL[2][r], bl)));
            float m = v;
            #pragma unroll
            for (int off = 1; off < 16; off <<= 1) m = fmaxf(m, __shfl_xor(m, off));
            float ex = __expf(v - m);
            float s = ex;
            #pragma unroll
            for (int off = 1; off < 16; off <<= 1) s += __shfl_xor(s, off);
            float o = (v - m) - __logf(s);
            long oidx = (long)node * 16 + nl;
            if (f32) ((float*)out)[oidx] = o;
            else     ((__hip_bfloat16*)out)[oidx] = __float2bfloat16(o);
        }
    }
}

extern "C" void kernel_launch(void* const* d_in, const int* in_sizes, int n_in,
                              void* d_out, int out_size, void* d_ws, size_t ws_size,
                              hipStream_t stream) {
    const void* x    = d_in[0];
    const int*  ei   = (const int*)d_in[1];
    const void* W1   = d_in[2];
    const void* b1   = d_in[3];
    const void* W2   = d_in[4];
    const void* b2   = d_in[5];
    const void* W3   = d_in[6];
    const void* b3   = d_in[7];
    const void* Wlin = d_in[8];
    const void* blin = d_in[9];

    // workspace layout (~38 MB)
    unsigned short* h   = (unsigned short*)d_ws;      // NPAD*64 bf16 (rows >=NN zero)
    unsigned short* emb = h + (long)NPAD * 64;        // 3 x N*64 bf16 (un-normalized)
    float* dis     = (float*)(emb + (long)3 * NN * 64); // N
    int*   row_ptr = (int*)(dis + NN);                // N+64
    int*   flag    = row_ptr + NN + 64;               // 16
    float* sumsq   = (float*)(flag + 16);             // 3*N (zeroed each launch)
    int*   bcur    = (int*)(sumsq + 3 * NN);          // NB*CPAD (line-padded)
    unsigned* bdata = (unsigned*)(bcur + NB * CPAD);  // NB*CAPB u32 (~7.2 MB)
    unsigned short* csr_col = (unsigned short*)(bdata + (long)NB * CAPB); // E u16

    const int* row = ei;        // edge_index[0] = targets
    const int* col = ei + EE;   // edge_index[1] = sources

    // zero sumsq (3N floats) + bcur (NB*CPAD ints) in one contiguous memset
    (void)hipMemsetAsync(sumsq, 0, (3 * NN + NB * CPAD) * sizeof(int), stream);
    k_bucket<<<(EE + EPB - 1) / EPB, 256, 0, stream>>>(row, col, bcur, bdata,
                                                       (const unsigned short*)x, flag);
    k_csr<<<NB, 256, 0, stream>>>(bcur, bdata, row_ptr, dis, csr_col);

    int gb = (NN + 63) / 64;    // 782 blocks -> covers nodes 0..50047 (= NPAD)
    // k_agg grid: 2 planes x 6250 node-groups, XCD-partitioned via bid&7.
    // grp = (bid>>3)*4 + (bid&3) must reach 6249 -> 1563 rounds of 8 blocks.
    int ga = 1563 * 8;
    const uint4* hp128 = (const uint4*)h;
    // layer 1 (input: external x, no deferred norm on input)
    k_gemm<true><<<gb, 256, 0, stream>>>(x, W1, flag, dis, nullptr, h);
    k_agg<<<ga, 256, 0, stream>>>(hp128, row_ptr, csr_col, dis, b1, flag,
                                  emb, sumsq);
    // layer 2 (input: raw emb layer 0 + deferred norm via sumsq[0])
    k_gemm<false><<<gb, 256, 0, stream>>>(emb, W2, flag, dis, sumsq, h);
    k_agg<<<ga, 256, 0, stream>>>(hp128, row_ptr, csr_col, dis, b2, flag,
                                  emb + (long)NN * 64, sumsq + NN);
    // layer 3 (input: raw emb layer 1 + deferred norm via sumsq[1])
    k_gemm<false><<<gb, 256, 0, stream>>>(emb + (long)NN * 64, W3, flag, dis,
                                          sumsq + NN, h);
    k_agg<<<ga, 256, 0, stream>>>(hp128, row_ptr, csr_col, dis, b3, flag,
                                  emb + (long)2 * NN * 64, sumsq + 2 * NN);

    k_out<<<gb, 256, 0, stream>>>(emb, Wlin, blin, flag, sumsq, d_out);
}

// Round 6
// 341.170 us; speedup vs baseline: 1.0485x; 1.0485x over previous
//
#include <hip/hip_runtime.h>
#include <hip/hip_bf16.h>

#define NN 50000
#define NPAD 50048   // h rows incl. zero rows 50000..50047 (gemm grid coverage)
#define EE 1600000
#define NB 391       // buckets of 128 rows (391*128 = 50048 >= NN)
#define CAPB 4608    // per-bucket global capacity; mean 4092, sd ~64 -> +8 sigma
#define CPAD 16      // one counter per 64B line
#define EPB 4096     // edges per k_bucket block -> 391 blocks
#define BCAP 28      // per-(block,bucket) LDS cap; mean 10.5 (+5.5 sigma, spill-safe)

typedef __attribute__((ext_vector_type(8))) short short8;
typedef __attribute__((ext_vector_type(4))) float floatx4;

// ---- dual-dtype load: external float tensors are either f32 or bf16 (flag).
__device__ __forceinline__ float ldext(const void* p, long i, int f32) {
    return f32 ? ((const float*)p)[i]
               : __bfloat162float(((const __hip_bfloat16*)p)[i]);
}

__device__ __forceinline__ float b2f(unsigned short u) {
    unsigned int x = ((unsigned int)u) << 16;
    float f; __builtin_memcpy(&f, &x, 4); return f;
}
__device__ __forceinline__ unsigned short f2b(float f) {
    __hip_bfloat16 h = __float2bfloat16(f);   // round-to-nearest-even
    unsigned short u; __builtin_memcpy(&u, &h, 2); return u;
}
__device__ __forceinline__ float asf(unsigned int x) {
    float f; __builtin_memcpy(&f, &x, 4); return f;
}

// ---------------- pass A: LDS binning + lane-parallel flush (+flag in blk 0) --
__global__ void k_bucket(const int* __restrict__ row, const int* __restrict__ col,
                         int* __restrict__ bcur, unsigned int* __restrict__ bdata,
                         const unsigned short* __restrict__ xu, int* __restrict__ flag) {
    __shared__ int lcnt[NB];
    __shared__ unsigned binned[NB * BCAP];   // ~43.8 KB
    __shared__ int dcnt;
    int tid = threadIdx.x;
    if (blockIdx.x == 0) {                   // input-dtype detection (once)
        if (tid == 0) dcnt = 0;
        __syncthreads();
        int local = 0;
        for (int j = 0; j < 16; ++j) {
            unsigned short u = xu[2 * (tid + 256 * j)];
            int ex = (u >> 7) & 0xFF;
            if (ex == 0xFF || ex < 0x60) local++;
        }
        atomicAdd(&dcnt, local);
        __syncthreads();
        if (tid == 0) flag[0] = (dcnt > 256) ? 1 : 0;
    }
    long base = (long)blockIdx.x * EPB;
    int nedge = (int)min((long)EPB, (long)EE - base);   // always multiple of 4
    for (int k = tid; k < NB; k += 256) lcnt[k] = 0;
    __syncthreads();
    const int4* r4 = (const int4*)(row + base);
    const int4* c4 = (const int4*)(col + base);
    for (int j = tid; j < (nedge >> 2); j += 256) {
        int4 rr = r4[j], cc = c4[j];
        #pragma unroll
        for (int t = 0; t < 4; ++t) {
            int r = (&rr.x)[t], c = (&cc.x)[t];
            int b = r >> 7;
            unsigned rec = ((unsigned)(r & 127) << 16) | (unsigned)c;
            int p = atomicAdd(&lcnt[b], 1);
            if (p < BCAP) binned[b * BCAP + p] = rec;
            else {                               // rare spill: direct global append
                int gp = atomicAdd(&bcur[b * CPAD], 1);
                if (gp < CAPB) bdata[(long)b * CAPB + gp] = rec;
            }
        }
    }
    __syncthreads();
    for (int b = tid; b < NB; b += 256) {
        int n = min(lcnt[b], BCAP);
        if (!n) continue;
        int gb = atomicAdd(&bcur[b * CPAD], n);
        long dst = (long)b * CAPB;
        for (int j = 0; j < n; ++j)
            if (gb + j < CAPB) bdata[dst + gb + j] = binned[b * BCAP + j];
    }
}

// ---------------- fused: degree count + prefix + row_ptr/dis + scatter -------
__global__ void k_csr(const int* __restrict__ bcur, const unsigned* __restrict__ bdata,
                      int* __restrict__ row_ptr, float* __restrict__ dis,
                      unsigned short* __restrict__ csr_col) {
    __shared__ unsigned recs[CAPB];          // 18.4 KB
    __shared__ int cnt[128];
    __shared__ int incl[128];
    __shared__ int curs[128];
    __shared__ int redu[4];
    int b = blockIdx.x, tid = threadIdx.x;
    int lane = tid & 63, wid = tid >> 6;
    int part = 0;
    for (int j = tid; j < b; j += 256) part += min(bcur[j * CPAD], CAPB);
    #pragma unroll
    for (int off = 32; off; off >>= 1) part += __shfl_xor(part, off);
    if (lane == 0) redu[wid] = part;
    if (tid < 128) cnt[tid] = 0;
    __syncthreads();
    int base = redu[0] + redu[1] + redu[2] + redu[3];
    int n = min(bcur[b * CPAD], CAPB);
    const unsigned* dp = bdata + (long)b * CAPB;
    for (int i = tid; i < n; i += 256) {
        unsigned rec = dp[i];
        recs[i] = rec;
        atomicAdd(&cnt[(rec >> 16) & 127], 1);
    }
    __syncthreads();
    if (tid < 128) {
        int x = cnt[tid];
        #pragma unroll
        for (int off = 1; off < 64; off <<= 1) {
            int y = __shfl_up(x, off);
            if (lane >= off) x += y;
        }
        incl[tid] = x;
    }
    __syncthreads();
    int r0 = b << 7;
    if (tid < 128) {
        int ic = incl[tid] + (wid == 1 ? incl[63] : 0);
        int excl = base + ic - cnt[tid];
        curs[tid] = excl;
        int r = r0 + tid;
        if (r <= NN) row_ptr[r] = excl;
        if (r < NN) dis[r] = rsqrtf((float)(cnt[tid] + 1));
    }
    __syncthreads();
    for (int i = tid; i < n; i += 256) {
        unsigned rec = recs[i];
        int p = atomicAdd(&curs[(rec >> 16) & 127], 1);
        csr_col[p] = (unsigned short)(rec & 0xFFFF);
    }
}

// ---------------- dense h' = dis_n * inv_prev * (X @ W), MFMA bf16 ----------
// Output is PLANE-MAJOR: plane0 = h[:,0:32] at Hout[0..NPAD*32), plane1 =
// h[:,32:64] at Hout[NPAD*32..). Separate address ranges -> separate L2 lines
// -> per-XCD hot set in k_agg is one 3.2 MB plane. Rows NN..NPAD-1 zero.
template <bool EXT>
__global__ void k_gemm(const void* __restrict__ X, const void* __restrict__ W,
                       const int* __restrict__ flag, const float* __restrict__ dis,
                       const float* __restrict__ sq,   // prev-layer sumsq (null if EXT)
                       unsigned short* __restrict__ Hout) {
    __shared__ __align__(16) unsigned short xs[64 * 72];
    int tid = threadIdx.x;
    int n0 = blockIdx.x * 64;
    const int f32 = flag[0];
    for (int idx = tid; idx < 4096; idx += 256) {
        int nn = idx >> 6, k = idx & 63;
        int n = n0 + nn;
        unsigned short v = 0;
        if (n < NN) {
            long ofs = (long)n * 64 + k;
            if (EXT) v = f32 ? f2b(((const float*)X)[ofs]) : ((const unsigned short*)X)[ofs];
            else     v = ((const unsigned short*)X)[ofs];
        }
        xs[nn * 72 + k] = v;
    }
    __syncthreads();
    int lane = tid & 63, wid = tid >> 6;
    int m0 = wid * 16;
    int quad = lane >> 4, nl = lane & 15;
    short8 a0 = *(const short8*)(xs + (m0 + nl) * 72 + quad * 8);
    short8 a1 = *(const short8*)(xs + (m0 + nl) * 72 + quad * 8 + 32);
    floatx4 acc[4];
    const unsigned short* Wb = (const unsigned short*)W;
    const float* Wf = (const float*)W;
    #pragma unroll
    for (int ct = 0; ct < 4; ++ct) {
        short8 b0, b1;
        int n = ct * 16 + nl;
        #pragma unroll
        for (int j = 0; j < 8; ++j) {
            int k0 = quad * 8 + j;
            b0[j] = (short)(f32 ? f2b(Wf[k0 * 64 + n]) : Wb[k0 * 64 + n]);
            b1[j] = (short)(f32 ? f2b(Wf[(k0 + 32) * 64 + n]) : Wb[(k0 + 32) * 64 + n]);
        }
        floatx4 c = {0.f, 0.f, 0.f, 0.f};
        c = __builtin_amdgcn_mfma_f32_16x16x32_bf16(a0, b0, c, 0, 0, 0);
        c = __builtin_amdgcn_mfma_f32_16x16x32_bf16(a1, b1, c, 0, 0, 0);
        acc[ct] = c;
    }
    #pragma unroll
    for (int r = 0; r < 4; ++r) {
        int node = n0 + m0 + quad * 4 + r;   // always < NPAD
        if (node < NN) {
            float dn = dis[node];
            if (!EXT) dn *= 1.f / fmaxf(sqrtf(sq[node]), 1e-12f);  // deferred l2norm
            #pragma unroll
            for (int ct = 0; ct < 4; ++ct) {
                long po = (ct >> 1) ? (long)NPAD * 32 : 0;   // plane-major
                Hout[po + (long)node * 32 + (ct & 1) * 16 + nl] = f2b(dn * acc[ct][r]);
            }
        } else {                              // zero pad rows NN..NPAD-1
            #pragma unroll
            for (int ct = 0; ct < 4; ++ct) {
                long po = (ct >> 1) ? (long)NPAD * 32 : 0;
                Hout[po + (long)node * 32 + (ct & 1) * 16 + nl] = 0;
            }
        }
    }
}

// ---------------- per-node aggregation + bias + relu (norm deferred) ---------
// XCD-partitioned feature planes over a PLANE-MAJOR h: blocks dispatch
// round-robin to XCDs (xcd = bid & 7). XCDs 0-3 gather only plane 0
// ([NPAD,32], 3.2 MB < 4 MB L2/XCD), XCDs 4-7 only plane 1 -> per-XCD
// L2-resident hot set. Writes UN-normalized relu'd bf16 + atomic per-node
// sumsq; the consumer applies the row scale (commutes with @W). Uniform
// 64-edge loop, 8 gathers of 64B rows in flight; pad slots clamp to zero row.
__global__ void k_agg(const uint4* __restrict__ hp128, const int* __restrict__ row_ptr,
                      const unsigned short* __restrict__ csr_col,
                      const float* __restrict__ dis, const void* __restrict__ bias,
                      const int* __restrict__ flag,
                      unsigned short* __restrict__ eo /* [N,64] bf16 raw */,
                      float* __restrict__ sq /* [N] sumsq */) {
    int lane = threadIdx.x & 63, wid = threadIdx.x >> 6;
    int bid = blockIdx.x;
    int plane = (bid >> 2) & 1;              // xcd = bid&7; plane = xcd>>2
    int grp = (bid >> 3) * 4 + (bid & 3);    // node group of 8
    int half = lane >> 5;
    int i = grp * 8 + wid * 2 + half;
    bool valid = (i < NN);
    int iv = valid ? i : 0;
    int q  = (lane >> 2) & 7;   // edge slot (8 per node)
    int fl = lane & 3;          // 16B chunk within the 64B plane row
    const uint4* hp = hp128 + (long)plane * NPAD * 4;  // plane base (uint4 units)
    float2 A0 = {0,0}, A1 = {0,0}, A2 = {0,0}, A3 = {0,0};
    #define ADDU(u) do { \
        A0.x += asf((u).x << 16); A0.y += asf((u).x & 0xFFFF0000u); \
        A1.x += asf((u).y << 16); A1.y += asf((u).y & 0xFFFF0000u); \
        A2.x += asf((u).z << 16); A2.y += asf((u).z & 0xFFFF0000u); \
        A3.x += asf((u).w << 16); A3.y += asf((u).w & 0xFFFF0000u); } while (0)
    if (valid && q == 0) {      // self-loop term
        uint4 u = hp[(long)iv * 4 + fl];
        ADDU(u);
    }
    int e  = valid ? row_ptr[iv] : 0;
    int e1 = valid ? row_ptr[iv + 1] : 0;
    while (e < e1) {
        int i0 = e + q,      i1 = e + 8 + q,  i2 = e + 16 + q, i3 = e + 24 + q;
        int i4 = e + 32 + q, i5 = e + 40 + q, i6 = e + 48 + q, i7 = e + 56 + q;
        int c0 = (i0 < e1) ? (int)__builtin_nontemporal_load(csr_col + i0) : NN;
        int c1 = (i1 < e1) ? (int)__builtin_nontemporal_load(csr_col + i1) : NN;
        int c2 = (i2 < e1) ? (int)__builtin_nontemporal_load(csr_col + i2) : NN;
        int c3 = (i3 < e1) ? (int)__builtin_nontemporal_load(csr_col + i3) : NN;
        int c4 = (i4 < e1) ? (int)__builtin_nontemporal_load(csr_col + i4) : NN;
        int c5 = (i5 < e1) ? (int)__builtin_nontemporal_load(csr_col + i5) : NN;
        int c6 = (i6 < e1) ? (int)__builtin_nontemporal_load(csr_col + i6) : NN;
        int c7 = (i7 < e1) ? (int)__builtin_nontemporal_load(csr_col + i7) : NN;
        uint4 u0 = hp[(long)c0 * 4 + fl];
        uint4 u1 = hp[(long)c1 * 4 + fl];
        uint4 u2 = hp[(long)c2 * 4 + fl];
        uint4 u3 = hp[(long)c3 * 4 + fl];
        uint4 u4 = hp[(long)c4 * 4 + fl];
        uint4 u5 = hp[(long)c5 * 4 + fl];
        uint4 u6 = hp[(long)c6 * 4 + fl];
        uint4 u7 = hp[(long)c7 * 4 + fl];
        ADDU(u0); ADDU(u1); ADDU(u2); ADDU(u3);
        ADDU(u4); ADDU(u5); ADDU(u6); ADDU(u7);
        e += 64;
    }
    #undef ADDU
    // butterfly over the 8 edge slots (lane bits 2..4)
    #pragma unroll
    for (int off = 4; off < 32; off <<= 1) {
        A0.x += __shfl_xor(A0.x, off); A0.y += __shfl_xor(A0.y, off);
        A1.x += __shfl_xor(A1.x, off); A1.y += __shfl_xor(A1.y, off);
        A2.x += __shfl_xor(A2.x, off); A2.y += __shfl_xor(A2.y, off);
        A3.x += __shfl_xor(A3.x, off); A3.y += __shfl_xor(A3.y, off);
    }
    const int f32 = flag[0];
    float di = dis[iv];
    int fb = plane * 32 + fl * 8;            // feature base for this lane
    float v0 = fmaf(di, A0.x, ldext(bias, fb + 0, f32));
    float v1 = fmaf(di, A0.y, ldext(bias, fb + 1, f32));
    float v2 = fmaf(di, A1.x, ldext(bias, fb + 2, f32));
    float v3 = fmaf(di, A1.y, ldext(bias, fb + 3, f32));
    float v4 = fmaf(di, A2.x, ldext(bias, fb + 4, f32));
    float v5 = fmaf(di, A2.y, ldext(bias, fb + 5, f32));
    float v6 = fmaf(di, A3.x, ldext(bias, fb + 6, f32));
    float v7 = fmaf(di, A3.y, ldext(bias, fb + 7, f32));
    v0 = fmaxf(v0, 0.f); v1 = fmaxf(v1, 0.f); v2 = fmaxf(v2, 0.f); v3 = fmaxf(v3, 0.f);
    v4 = fmaxf(v4, 0.f); v5 = fmaxf(v5, 0.f); v6 = fmaxf(v6, 0.f); v7 = fmaxf(v7, 0.f);
    float s = fmaf(v0, v0, fmaf(v1, v1, fmaf(v2, v2, v3 * v3)))
            + fmaf(v4, v4, fmaf(v5, v5, fmaf(v6, v6, v7 * v7)));
    // reduce partial sumsq across the 4 fl lanes (within the q==0 group)
    s += __shfl_xor(s, 1);
    s += __shfl_xor(s, 2);
    if (valid && q == 0) {
        union { unsigned short us[8]; uint4 v; } pk;
        pk.us[0] = f2b(v0); pk.us[1] = f2b(v1);
        pk.us[2] = f2b(v2); pk.us[3] = f2b(v3);
        pk.us[4] = f2b(v4); pk.us[5] = f2b(v5);
        pk.us[6] = f2b(v6); pk.us[7] = f2b(v7);
        *(uint4*)(eo + (long)i * 64 + fb) = pk.v;
        if (fl == 0) atomicAdd(&sq[i], s);
    }
}

// ---------------- head: emb @ Wlin + blin + log_softmax, MFMA ----------------
// emb holds UN-normalized layer outputs; per-layer row scale invL applied to
// each layer's partial MFMA accumulator (scale commutes with @Wlin segment).
__global__ void k_out(const unsigned short* __restrict__ emb, const void* __restrict__ Wlin,
                      const void* __restrict__ blin, const int* __restrict__ flag,
                      const float* __restrict__ sumsq /* [3][N] */,
                      void* __restrict__ out) {
    int tid = threadIdx.x, lane = tid & 63, wid = tid >> 6;
    int quad = lane >> 4, nl = lane & 15;
    int base = blockIdx.x * 64 + wid * 16;
    const int f32 = flag[0];
    const unsigned short* Wb = (const unsigned short*)Wlin;
    const float* Wf = (const float*)Wlin;
    int ia = min(base + nl, NN - 1);     // A-row node (guarded store later)
    floatx4 cL[3];
    #pragma unroll
    for (int L = 0; L < 3; ++L) cL[L] = floatx4{0.f, 0.f, 0.f, 0.f};
    #pragma unroll
    for (int L = 0; L < 3; ++L) {
        #pragma unroll
        for (int kh = 0; kh < 2; ++kh) {
            short8 b;
            #pragma unroll
            for (int j = 0; j < 8; ++j) {
                int k = L * 64 + kh * 32 + quad * 8 + j;
                b[j] = (short)(f32 ? f2b(Wf[k * 16 + nl]) : Wb[k * 16 + nl]);
            }
            int ko = kh * 32 + quad * 8;
            short8 a = *(const short8*)(emb + (long)L * NN * 64 + (long)ia * 64 + ko);
            cL[L] = __builtin_amdgcn_mfma_f32_16x16x32_bf16(a, b, cL[L], 0, 0, 0);
        }
    }
    float bl = ldext(blin, nl, f32);
    #pragma unroll
    for (int r = 0; r < 4; ++r) {
        int node = base + quad * 4 + r;    // uniform across the 16 nl lanes
        if (node < NN) {
            float i0 = 1.f / fmaxf(sqrtf(sumsq[node]), 1e-12f);
            float i1 = 1.f / fmaxf(sqrtf(sumsq[NN + node]), 1e-12f);
            float i2 = 1.f / fmaxf(sqrtf(sumsq[2 * NN + node]), 1e-12f);
            float v = fmaf(i0, cL[0][r], fmaf(i1, cL[1][r], fmaf(i2, cL[2][r], bl)));
            float m = v;
            #pragma unroll
            for (int off = 1; off < 16; off <<= 1) m = fmaxf(m, __shfl_xor(m, off));
            float ex = __expf(v - m);
            float s = ex;
            #pragma unroll
            for (int off = 1; off < 16; off <<= 1) s += __shfl_xor(s, off);
            float o = (v - m) - __logf(s);
            long oidx = (long)node * 16 + nl;
            if (f32) ((float*)out)[oidx] = o;
            else     ((__hip_bfloat16*)out)[oidx] = __float2bfloat16(o);
        }
    }
}

extern "C" void kernel_launch(void* const* d_in, const int* in_sizes, int n_in,
                              void* d_out, int out_size, void* d_ws, size_t ws_size,
                              hipStream_t stream) {
    const void* x    = d_in[0];
    const int*  ei   = (const int*)d_in[1];
    const void* W1   = d_in[2];
    const void* b1   = d_in[3];
    const void* W2   = d_in[4];
    const void* b2   = d_in[5];
    const void* W3   = d_in[6];
    const void* b3   = d_in[7];
    const void* Wlin = d_in[8];
    const void* blin = d_in[9];

    // workspace layout (~38 MB)
    unsigned short* h   = (unsigned short*)d_ws;      // 2 planes x NPAD x 32 bf16
    unsigned short* emb = h + (long)NPAD * 64;        // 3 x N*64 bf16 (un-normalized)
    float* dis     = (float*)(emb + (long)3 * NN * 64); // N
    int*   row_ptr = (int*)(dis + NN);                // N+64
    int*   flag    = row_ptr + NN + 64;               // 16
    float* sumsq   = (float*)(flag + 16);             // 3*N (zeroed each launch)
    int*   bcur    = (int*)(sumsq + 3 * NN);          // NB*CPAD (line-padded)
    unsigned* bdata = (unsigned*)(bcur + NB * CPAD);  // NB*CAPB u32 (~7.2 MB)
    unsigned short* csr_col = (unsigned short*)(bdata + (long)NB * CAPB); // E u16

    const int* row = ei;        // edge_index[0] = targets
    const int* col = ei + EE;   // edge_index[1] = sources

    // zero sumsq (3N floats) + bcur (NB*CPAD ints) in one contiguous memset
    (void)hipMemsetAsync(sumsq, 0, (3 * NN + NB * CPAD) * sizeof(int), stream);
    k_bucket<<<(EE + EPB - 1) / EPB, 256, 0, stream>>>(row, col, bcur, bdata,
                                                       (const unsigned short*)x, flag);
    k_csr<<<NB, 256, 0, stream>>>(bcur, bdata, row_ptr, dis, csr_col);

    int gb = (NN + 63) / 64;    // 782 blocks -> covers nodes 0..50047 (= NPAD)
    // k_agg grid: 2 planes x 6250 node-groups, XCD-partitioned via bid&7.
    // grp = (bid>>3)*4 + (bid&3) covers [0,6252); 1563 rounds of 8 blocks.
    int ga = 1563 * 8;
    const uint4* hp128 = (const uint4*)h;
    // layer 1 (input: external x, no deferred norm on input)
    k_gemm<true><<<gb, 256, 0, stream>>>(x, W1, flag, dis, nullptr, h);
    k_agg<<<ga, 256, 0, stream>>>(hp128, row_ptr, csr_col, dis, b1, flag,
                                  emb, sumsq);
    // layer 2 (input: raw emb layer 0 + deferred norm via sumsq[0])
    k_gemm<false><<<gb, 256, 0, stream>>>(emb, W2, flag, dis, sumsq, h);
    k_agg<<<ga, 256, 0, stream>>>(hp128, row_ptr, csr_col, dis, b2, flag,
                                  emb + (long)NN * 64, sumsq + NN);
    // layer 3 (input: raw emb layer 1 + deferred norm via sumsq[1])
    k_gemm<false><<<gb, 256, 0, stream>>>(emb + (long)NN * 64, W3, flag, dis,
                                          sumsq + NN, h);
    k_agg<<<ga, 256, 0, stream>>>(hp128, row_ptr, csr_col, dis, b3, flag,
                                  emb + (long)2 * NN * 64, sumsq + 2 * NN);

    k_out<<<gb, 256, 0, stream>>>(emb, Wlin, blin, flag, sumsq, d_out);
}

// Round 7
// 273.059 us; speedup vs baseline: 1.3100x; 1.2494x over previous
//
#include <hip/hip_runtime.h>
#include <hip/hip_bf16.h>

#define NN 50000
#define NPAD 50048   // h rows incl. zero rows 50000..50047 (gemm grid coverage)
#define EE 1600000
#define NB 391       // buckets of 128 rows (391*128 = 50048 >= NN)
#define CAPB 4608    // per-bucket record capacity; mean 4092, sd ~64 -> +8 sigma
#define CPAD 16      // one counter per 64B line
#define EPB 4096     // edges per k_bucket block -> 391 blocks
#define BCAP 28      // per-(block,bucket) LDS cap; mean 10.5 (+5.5 sigma, spill-safe)
#define PBCAP 7424   // padded CSR slots per bucket; mean 5939, sd ~180 -> +8 sigma

typedef __attribute__((ext_vector_type(8))) short short8;
typedef __attribute__((ext_vector_type(4))) float floatx4;

// ---- dual-dtype load: external float tensors are either f32 or bf16 (flag).
__device__ __forceinline__ float ldext(const void* p, long i, int f32) {
    return f32 ? ((const float*)p)[i]
               : __bfloat162float(((const __hip_bfloat16*)p)[i]);
}

__device__ __forceinline__ unsigned short f2b(float f) {
    __hip_bfloat16 h = __float2bfloat16(f);   // round-to-nearest-even
    unsigned short u; __builtin_memcpy(&u, &h, 2); return u;
}
__device__ __forceinline__ float asf(unsigned int x) {
    float f; __builtin_memcpy(&f, &x, 4); return f;
}

// ---------------- pass A: LDS binning + lane-parallel flush (+flag in blk 0) --
__global__ void k_bucket(const int* __restrict__ row, const int* __restrict__ col,
                         int* __restrict__ bcur, unsigned int* __restrict__ bdata,
                         const unsigned short* __restrict__ xu, int* __restrict__ flag) {
    __shared__ int lcnt[NB];
    __shared__ unsigned binned[NB * BCAP];   // ~43.8 KB
    __shared__ int dcnt;
    int tid = threadIdx.x;
    if (blockIdx.x == 0) {                   // input-dtype detection (once)
        if (tid == 0) dcnt = 0;
        __syncthreads();
        int local = 0;
        for (int j = 0; j < 16; ++j) {
            unsigned short u = xu[2 * (tid + 256 * j)];
            int ex = (u >> 7) & 0xFF;
            if (ex == 0xFF || ex < 0x60) local++;
        }
        atomicAdd(&dcnt, local);
        __syncthreads();
        if (tid == 0) flag[0] = (dcnt > 256) ? 1 : 0;
    }
    long base = (long)blockIdx.x * EPB;
    int nedge = (int)min((long)EPB, (long)EE - base);   // always multiple of 4
    for (int k = tid; k < NB; k += 256) lcnt[k] = 0;
    __syncthreads();
    const int4* r4 = (const int4*)(row + base);
    const int4* c4 = (const int4*)(col + base);
    for (int j = tid; j < (nedge >> 2); j += 256) {
        int4 rr = r4[j], cc = c4[j];
        #pragma unroll
        for (int t = 0; t < 4; ++t) {
            int r = (&rr.x)[t], c = (&cc.x)[t];
            int b = r >> 7;
            unsigned rec = ((unsigned)(r & 127) << 16) | (unsigned)c;
            int p = atomicAdd(&lcnt[b], 1);
            if (p < BCAP) binned[b * BCAP + p] = rec;
            else {                               // rare spill: direct global append
                int gp = atomicAdd(&bcur[b * CPAD], 1);
                if (gp < CAPB) bdata[(long)b * CAPB + gp] = rec;
            }
        }
    }
    __syncthreads();
    for (int b = tid; b < NB; b += 256) {
        int n = min(lcnt[b], BCAP);
        if (!n) continue;
        int gb = atomicAdd(&bcur[b * CPAD], n);
        long dst = (long)b * CAPB;
        for (int j = 0; j < n; ++j)
            if (gb + j < CAPB) bdata[dst + gb + j] = binned[b * BCAP + j];
    }
}

// ---------------- fused: degree count + padded CSR build ---------------------
// Per-bucket FIXED region [b*PBCAP, (b+1)*PBCAP): no cross-bucket prefix.
// Each node's edge list padded to a multiple of 32 slots with index NN (the
// zero row), so k_agg's inner loop needs no per-slot bounds checks and can
// load 8 indices with one uint4.
__global__ void k_csr(const int* __restrict__ bcur, const unsigned* __restrict__ bdata,
                      int* __restrict__ rp0, int* __restrict__ degA,
                      float* __restrict__ dis, unsigned short* __restrict__ csr_col) {
    __shared__ unsigned recs[CAPB];          // 18.4 KB
    __shared__ int cnt[128];
    __shared__ int incl[128];
    __shared__ int curs[128];
    int b = blockIdx.x, tid = threadIdx.x;
    int lane = tid & 63, wid = tid >> 6;
    if (tid < 128) cnt[tid] = 0;
    __syncthreads();
    int n = min(bcur[b * CPAD], CAPB);
    const unsigned* dp = bdata + (long)b * CAPB;
    for (int i = tid; i < n; i += 256) {
        unsigned rec = dp[i];
        recs[i] = rec;
        atomicAdd(&cnt[(rec >> 16) & 127], 1);
    }
    __syncthreads();
    if (tid < 128) {
        int x = (cnt[tid] + 31) & ~31;       // padded degree
        #pragma unroll
        for (int off = 1; off < 64; off <<= 1) {
            int y = __shfl_up(x, off);
            if (lane >= off) x += y;
        }
        incl[tid] = x;
    }
    __syncthreads();
    int r0 = b << 7;
    int lim = (b + 1) * PBCAP;
    if (tid < 128) {
        int c = cnt[tid];
        int x = (c + 31) & ~31;
        int ic = incl[tid] + (wid == 1 ? incl[63] : 0);
        int excl = b * PBCAP + ic - x;
        curs[tid] = excl;
        int r = r0 + tid;
        if (r < NN) {
            rp0[r] = excl;
            degA[r] = c;
            dis[r] = rsqrtf((float)(c + 1));
        }
        for (int j = c; j < x && excl + j < lim; ++j)
            csr_col[excl + j] = (unsigned short)NN;   // pad -> zero row
    }
    __syncthreads();
    for (int i = tid; i < n; i += 256) {
        unsigned rec = recs[i];
        int p = atomicAdd(&curs[(rec >> 16) & 127], 1);
        if (p < lim) csr_col[p] = (unsigned short)(rec & 0xFFFF);
    }
}

// ---------------- dense h' = dis_n * (X @ W), MFMA bf16, W staged in LDS ----
// Rows NN..NPAD-1 are written as zeros (zero row for padded gathers).
template <bool EXT>
__global__ void k_gemm(const void* __restrict__ X, const void* __restrict__ W,
                       const int* __restrict__ flag, const float* __restrict__ dis,
                       unsigned short* __restrict__ Hout) {
    __shared__ __align__(16) unsigned short xs[64 * 72];
    __shared__ __align__(16) unsigned short ws[64 * 72];  // W transposed: ws[n*72+k]
    int tid = threadIdx.x;
    int n0 = blockIdx.x * 64;
    const int f32 = flag[0];
    const unsigned short* Wb = (const unsigned short*)W;
    const float* Wf = (const float*)W;
    for (int idx = tid; idx < 4096; idx += 256) {
        int nn = idx >> 6, k = idx & 63;
        int n = n0 + nn;
        unsigned short v = 0;
        if (n < NN) {
            long ofs = (long)n * 64 + k;
            if (EXT) v = f32 ? f2b(((const float*)X)[ofs]) : ((const unsigned short*)X)[ofs];
            else     v = ((const unsigned short*)X)[ofs];
        }
        xs[nn * 72 + k] = v;
        // stage W transposed (convert once; kills per-lane scalar W loads)
        int wk = idx >> 6, wn = idx & 63;
        ws[wn * 72 + wk] = f32 ? f2b(Wf[idx]) : Wb[idx];
    }
    __syncthreads();
    int lane = tid & 63, wid = tid >> 6;
    int m0 = wid * 16;
    int quad = lane >> 4, nl = lane & 15;
    short8 a0 = *(const short8*)(xs + (m0 + nl) * 72 + quad * 8);
    short8 a1 = *(const short8*)(xs + (m0 + nl) * 72 + quad * 8 + 32);
    floatx4 acc[4];
    #pragma unroll
    for (int ct = 0; ct < 4; ++ct) {
        int n = ct * 16 + nl;
        short8 b0 = *(const short8*)(ws + n * 72 + quad * 8);
        short8 b1 = *(const short8*)(ws + n * 72 + quad * 8 + 32);
        floatx4 c = {0.f, 0.f, 0.f, 0.f};
        c = __builtin_amdgcn_mfma_f32_16x16x32_bf16(a0, b0, c, 0, 0, 0);
        c = __builtin_amdgcn_mfma_f32_16x16x32_bf16(a1, b1, c, 0, 0, 0);
        acc[ct] = c;
    }
    #pragma unroll
    for (int r = 0; r < 4; ++r) {
        int node = n0 + m0 + quad * 4 + r;   // always < NPAD
        if (node < NN) {
            float dn = dis[node];
            #pragma unroll
            for (int ct = 0; ct < 4; ++ct)
                Hout[(long)node * 64 + ct * 16 + nl] = f2b(dn * acc[ct][r]);
        } else {                              // zero pad rows NN..NPAD-1
            #pragma unroll
            for (int ct = 0; ct < 4; ++ct)
                Hout[(long)node * 64 + ct * 16 + nl] = 0;
        }
    }
}

// ---------------- per-node aggregation + bias + relu + l2norm ----------------
// Padded CSR: per node, windows of 32 slots, all real-or-NN. Inner loop per
// lane: ONE uint4 index load (8 indices) + 8 gathers (128B rows, 8 lanes/edge)
// + 8 unpack-accumulates. No compares, no clamps, 8 gathers in flight.
__global__ void k_agg(const uint4* __restrict__ hp128, const int* __restrict__ rp0,
                      const int* __restrict__ degA, const float* __restrict__ dis,
                      const unsigned short* __restrict__ csr_col,
                      const void* __restrict__ bias, const int* __restrict__ flag,
                      unsigned short* __restrict__ eo /* [N,64] bf16 */) {
    int lane = threadIdx.x & 63, wid = threadIdx.x >> 6;
    int half = lane >> 5;
    int i = blockIdx.x * 8 + wid * 2 + half;
    bool valid = (i < NN);
    int iv = valid ? i : 0;
    int q4 = (lane >> 3) & 3;   // edge-slot octet within half
    int fl = lane & 7;          // feature octet 8fl..8fl+7
    float2 A0 = {0,0}, A1 = {0,0}, A2 = {0,0}, A3 = {0,0};
    #define ADDU(u) do { \
        A0.x += asf((u).x << 16); A0.y += asf((u).x & 0xFFFF0000u); \
        A1.x += asf((u).y << 16); A1.y += asf((u).y & 0xFFFF0000u); \
        A2.x += asf((u).z << 16); A2.y += asf((u).z & 0xFFFF0000u); \
        A3.x += asf((u).w << 16); A3.y += asf((u).w & 0xFFFF0000u); } while (0)
    if (valid && q4 == 0) {     // self-loop term
        uint4 u = hp128[(long)iv * 8 + fl];
        ADDU(u);
    }
    int e0 = rp0[iv];
    int pd = (degA[iv] + 31) & ~31;          // padded degree (multiple of 32)
    const unsigned short* cb = csr_col + e0 + q4 * 8;  // 16B-aligned
    for (int t = 0; t < pd; t += 32) {
        uint4 I = *(const uint4*)(cb + t);   // 8 u16 indices, broadcast over fl
        int c0 = (int)(I.x & 0xFFFFu), c1 = (int)(I.x >> 16);
        int c2 = (int)(I.y & 0xFFFFu), c3 = (int)(I.y >> 16);
        int c4 = (int)(I.z & 0xFFFFu), c5 = (int)(I.z >> 16);
        int c6 = (int)(I.w & 0xFFFFu), c7 = (int)(I.w >> 16);
        uint4 u0 = hp128[(long)c0 * 8 + fl];
        uint4 u1 = hp128[(long)c1 * 8 + fl];
        uint4 u2 = hp128[(long)c2 * 8 + fl];
        uint4 u3 = hp128[(long)c3 * 8 + fl];
        uint4 u4 = hp128[(long)c4 * 8 + fl];
        uint4 u5 = hp128[(long)c5 * 8 + fl];
        uint4 u6 = hp128[(long)c6 * 8 + fl];
        uint4 u7 = hp128[(long)c7 * 8 + fl];
        ADDU(u0); ADDU(u1); ADDU(u2); ADDU(u3);
        ADDU(u4); ADDU(u5); ADDU(u6); ADDU(u7);
    }
    #undef ADDU
    // reduce over the 4 q4 slots (lane bits 3,4)
    #pragma unroll
    for (int off = 8; off < 32; off <<= 1) {
        A0.x += __shfl_xor(A0.x, off); A0.y += __shfl_xor(A0.y, off);
        A1.x += __shfl_xor(A1.x, off); A1.y += __shfl_xor(A1.y, off);
        A2.x += __shfl_xor(A2.x, off); A2.y += __shfl_xor(A2.y, off);
        A3.x += __shfl_xor(A3.x, off); A3.y += __shfl_xor(A3.y, off);
    }
    const int f32 = flag[0];
    float di = dis[iv];
    float v0 = fmaf(di, A0.x, ldext(bias, 8 * fl + 0, f32));
    float v1 = fmaf(di, A0.y, ldext(bias, 8 * fl + 1, f32));
    float v2 = fmaf(di, A1.x, ldext(bias, 8 * fl + 2, f32));
    float v3 = fmaf(di, A1.y, ldext(bias, 8 * fl + 3, f32));
    float v4 = fmaf(di, A2.x, ldext(bias, 8 * fl + 4, f32));
    float v5 = fmaf(di, A2.y, ldext(bias, 8 * fl + 5, f32));
    float v6 = fmaf(di, A3.x, ldext(bias, 8 * fl + 6, f32));
    float v7 = fmaf(di, A3.y, ldext(bias, 8 * fl + 7, f32));
    v0 = fmaxf(v0, 0.f); v1 = fmaxf(v1, 0.f); v2 = fmaxf(v2, 0.f); v3 = fmaxf(v3, 0.f);
    v4 = fmaxf(v4, 0.f); v5 = fmaxf(v5, 0.f); v6 = fmaxf(v6, 0.f); v7 = fmaxf(v7, 0.f);
    float s = fmaf(v0, v0, fmaf(v1, v1, fmaf(v2, v2, v3 * v3)))
            + fmaf(v4, v4, fmaf(v5, v5, fmaf(v6, v6, v7 * v7)));
    #pragma unroll
    for (int off = 4; off; off >>= 1) s += __shfl_xor(s, off);
    float inv = 1.f / fmaxf(sqrtf(s), 1e-12f);
    if (valid && q4 == 0) {
        union { unsigned short us[8]; uint4 v; } pk;
        pk.us[0] = f2b(v0 * inv); pk.us[1] = f2b(v1 * inv);
        pk.us[2] = f2b(v2 * inv); pk.us[3] = f2b(v3 * inv);
        pk.us[4] = f2b(v4 * inv); pk.us[5] = f2b(v5 * inv);
        pk.us[6] = f2b(v6 * inv); pk.us[7] = f2b(v7 * inv);
        *(uint4*)(eo + (long)i * 64 + 8 * fl) = pk.v;
    }
}

// ---------------- head: emb @ Wlin + blin + log_softmax, MFMA ----------------
__global__ void k_out(const unsigned short* __restrict__ emb, const void* __restrict__ Wlin,
                      const void* __restrict__ blin, const int* __restrict__ flag,
                      void* __restrict__ out) {
    int tid = threadIdx.x, lane = tid & 63, wid = tid >> 6;
    int quad = lane >> 4, nl = lane & 15;
    int base = blockIdx.x * 64 + wid * 16;
    const int f32 = flag[0];
    const unsigned short* Wb = (const unsigned short*)Wlin;
    const float* Wf = (const float*)Wlin;
    int ia = min(base + nl, NN - 1);     // A-row node (guarded store later)
    floatx4 c = {0.f, 0.f, 0.f, 0.f};
    #pragma unroll
    for (int kc = 0; kc < 6; ++kc) {
        short8 b;
        #pragma unroll
        for (int j = 0; j < 8; ++j) {
            int k = kc * 32 + quad * 8 + j;
            b[j] = (short)(f32 ? f2b(Wf[k * 16 + nl]) : Wb[k * 16 + nl]);
        }
        int L = kc >> 1, ko = (kc & 1) * 32 + quad * 8;
        short8 a = *(const short8*)(emb + (long)L * NN * 64 + (long)ia * 64 + ko);
        c = __builtin_amdgcn_mfma_f32_16x16x32_bf16(a, b, c, 0, 0, 0);
    }
    float bl = ldext(blin, nl, f32);
    #pragma unroll
    for (int r = 0; r < 4; ++r) {
        float v = c[r] + bl;
        float m = v;
        #pragma unroll
        for (int off = 1; off < 16; off <<= 1) m = fmaxf(m, __shfl_xor(m, off));
        float ex = __expf(v - m);
        float s = ex;
        #pragma unroll
        for (int off = 1; off < 16; off <<= 1) s += __shfl_xor(s, off);
        float o = (v - m) - __logf(s);
        int node = base + quad * 4 + r;
        if (node < NN) {
            long oidx = (long)node * 16 + nl;
            if (f32) ((float*)out)[oidx] = o;
            else     ((__hip_bfloat16*)out)[oidx] = __float2bfloat16(o);
        }
    }
}

extern "C" void kernel_launch(void* const* d_in, const int* in_sizes, int n_in,
                              void* d_out, int out_size, void* d_ws, size_t ws_size,
                              hipStream_t stream) {
    const void* x    = d_in[0];
    const int*  ei   = (const int*)d_in[1];
    const void* W1   = d_in[2];
    const void* b1   = d_in[3];
    const void* W2   = d_in[4];
    const void* b2   = d_in[5];
    const void* W3   = d_in[6];
    const void* b3   = d_in[7];
    const void* Wlin = d_in[8];
    const void* blin = d_in[9];

    // workspace layout (~39.3 MB)
    unsigned short* h   = (unsigned short*)d_ws;      // NPAD*64 bf16 (rows >=NN zero)
    unsigned short* emb = h + (long)NPAD * 64;        // 3 x N*64 bf16 (normalized)
    float* dis     = (float*)(emb + (long)3 * NN * 64); // N
    int*   rp0     = (int*)(dis + NN);                // N  (padded CSR row starts)
    int*   degA    = rp0 + NN;                        // N  (real degrees)
    int*   flag    = degA + NN;                       // 16
    int*   bcur    = flag + 16;                       // NB*CPAD (line-padded)
    unsigned* bdata = (unsigned*)(bcur + NB * CPAD);  // NB*CAPB u32 (~7.2 MB)
    unsigned short* csr_col = (unsigned short*)(bdata + (long)NB * CAPB); // NB*PBCAP u16

    const int* row = ei;        // edge_index[0] = targets
    const int* col = ei + EE;   // edge_index[1] = sources

    (void)hipMemsetAsync(bcur, 0, NB * CPAD * sizeof(int), stream);
    k_bucket<<<(EE + EPB - 1) / EPB, 256, 0, stream>>>(row, col, bcur, bdata,
                                                       (const unsigned short*)x, flag);
    k_csr<<<NB, 256, 0, stream>>>(bcur, bdata, rp0, degA, dis, csr_col);

    int gb = (NN + 63) / 64;    // 782 blocks -> covers nodes 0..50047 (= NPAD)
    int ga = (NN + 7) / 8;      // 6250 blocks
    const uint4* hp128 = (const uint4*)h;
    // layer 1 (input: external x)
    k_gemm<true><<<gb, 256, 0, stream>>>(x, W1, flag, dis, h);
    k_agg<<<ga, 256, 0, stream>>>(hp128, rp0, degA, dis, csr_col, b1, flag, emb);
    // layer 2 (input: emb layer 0, bf16)
    k_gemm<false><<<gb, 256, 0, stream>>>(emb, W2, flag, dis, h);
    k_agg<<<ga, 256, 0, stream>>>(hp128, rp0, degA, dis, csr_col, b2, flag,
                                  emb + (long)NN * 64);
    // layer 3 (input: emb layer 1, bf16)
    k_gemm<false><<<gb, 256, 0, stream>>>(emb + (long)NN * 64, W3, flag, dis, h);
    k_agg<<<ga, 256, 0, stream>>>(hp128, rp0, degA, dis, csr_col, b3, flag,
                                  emb + (long)2 * NN * 64);

    k_out<<<gb, 256, 0, stream>>>(emb, Wlin, blin, flag, d_out);
}